// Round 13
// baseline (61374.231 us; speedup 1.0000x reference)
//
#include <hip/hip_runtime.h>
#include <math.h>

#define TMAX 200
#define CB   64

__device__ __forceinline__ float sig_(float x){ return 1.0f/(1.0f+expf(-x)); }

// Light cluster barrier (proven R10): one atomicAdd + go flag, single poller.
__device__ __forceinline__ void cl_sync(int* cnt, int* go, int nblk, int ep, int tid)
{
    __syncthreads();
    if (tid == 0) {
        __threadfence();
        int old = __hip_atomic_fetch_add(cnt, 1, __ATOMIC_ACQ_REL, __HIP_MEMORY_SCOPE_AGENT);
        if (old == nblk - 1) {
            __hip_atomic_store(cnt, 0, __ATOMIC_RELAXED, __HIP_MEMORY_SCOPE_AGENT);
            __hip_atomic_store(go, ep, __ATOMIC_RELEASE, __HIP_MEMORY_SCOPE_AGENT);
        } else {
            while (__hip_atomic_load(go, __ATOMIC_ACQUIRE, __HIP_MEMORY_SCOPE_AGENT) < ep)
                __builtin_amdgcn_s_sleep(16);
        }
        __threadfence();
    }
    __syncthreads();
}

// LDS floats: XS @0 (A/B [32][68]=2176; C [2][32][68]=4352);
//             WS @4352 (A [48][36]=1728, B [32][36]=1152, C [16][36]=576);
//             HB/EX @6144 ([16][68]=1088).  Total 7424 f = 29.7 KB.
#define OWS 4352
#define OHB 6144
#define LDSF 7424

__global__ __launch_bounds__(256, 2)
void kfused(const int* __restrict__ lengths,
            const float* __restrict__ eps,
            const float* __restrict__ W_ih, const float* __restrict__ b_ih,
            const float* __restrict__ b_hh,
            const float* __restrict__ W1a, const float* __restrict__ b1a,
            const float* __restrict__ W1b, const float* __restrict__ b1b,
            const float* __restrict__ W2a, const float* __restrict__ b2a,
            const float* __restrict__ W2b, const float* __restrict__ b2b,
            float* __restrict__ out_p1, float* __restrict__ out_p2, float* __restrict__ out_h,
            int* __restrict__ bar, float* __restrict__ xT, float* __restrict__ hT,
            float* __restrict__ haT, int nblk)
{
    __shared__ float lds[LDSF];
    __shared__ int sbs[TMAX], soff[TMAX];

    const int tid = threadIdx.x;
    const int bid = blockIdx.x;
    const int wv  = __builtin_amdgcn_readfirstlane(tid >> 6);   // 0..3
    const int l   = tid & 63;            // lane = batch within cluster
    const int cl  = bid & 7;             // 8 clusters x 64 batches
    const int r   = bid >> 3;            // rank in cluster
    const int cb  = cl * CB;

    int* cnt = &bar[cl * 16];
    int* go  = &bar[cl * 16 + 8];

    if (tid < TMAX) {
        int c = 0;
        for (int b = 0; b < 512; ++b) c += (lengths[b] > tid) ? 1 : 0;
        sbs[tid] = c;
    }
    __syncthreads();
    if (tid == 0) { int a = 0; for (int i = 0; i < TMAX; ++i) { soff[i] = a; a += sbs[i]; } }
    __syncthreads();

    for (int t = 0; t < TMAX; ++t) {
        const int bsz = sbs[t], ofs = soff[t];

        // ========= phase A: gi = x@W_ih^T -> GRU (in-register) -> h ; 64 units x 16 j =========
        for (int s = r; s < 64; s += nblk) {
            const int j0 = s * 16;
            float acc[12];
            #pragma unroll
            for (int i = 0; i < 12; ++i) acc[i] = 0.f;

            if (t > 0) {
                const int xk = tid >> 3, xb = (tid & 7) * 8;
                const int wi1 = tid + 256;
                const int row0 = tid >> 3, k40 = (tid & 7) * 4;
                const int g0 = row0 >> 4, jj0 = row0 & 15;
                const int row1 = wi1 >> 3, k41 = (wi1 & 7) * 4;
                const int g1 = row1 >> 4, jj1 = row1 & 15;
                float4 px0, px1, pw0, pw1;
                {
                    const float* xp = &xT[(size_t)xk * 512 + cb + xb];
                    px0 = *(const float4*)xp; px1 = *(const float4*)(xp + 4);
                    pw0 = *(const float4*)&W_ih[(size_t)(g0*1024 + j0 + jj0) * 256 + k40];
                    if (wi1 < 384)
                        pw1 = *(const float4*)&W_ih[(size_t)(g1*1024 + j0 + jj1) * 256 + k41];
                }
                for (int kc = 0; kc < 8; ++kc) {
                    *(float4*)&lds[xk * 68 + xb]     = px0;
                    *(float4*)&lds[xk * 68 + xb + 4] = px1;
                    *(float4*)&lds[OWS + row0 * 36 + k40] = pw0;
                    if (wi1 < 384) *(float4*)&lds[OWS + row1 * 36 + k41] = pw1;
                    __syncthreads();
                    if (kc < 7) {
                        const int kb = (kc + 1) * 32;
                        const float* xp = &xT[(size_t)(kb + xk) * 512 + cb + xb];
                        px0 = *(const float4*)xp; px1 = *(const float4*)(xp + 4);
                        pw0 = *(const float4*)&W_ih[(size_t)(g0*1024 + j0 + jj0) * 256 + kb + k40];
                        if (wi1 < 384)
                            pw1 = *(const float4*)&W_ih[(size_t)(g1*1024 + j0 + jj1) * 256 + kb + k41];
                    }
                    #pragma unroll
                    for (int g4 = 0; g4 < 8; ++g4) {
                        const float x0 = lds[(g4*4+0)*68 + l];
                        const float x1 = lds[(g4*4+1)*68 + l];
                        const float x2 = lds[(g4*4+2)*68 + l];
                        const float x3 = lds[(g4*4+3)*68 + l];
                        #pragma unroll
                        for (int jq = 0; jq < 4; ++jq) {
                            #pragma unroll
                            for (int g = 0; g < 3; ++g) {
                                const int row = g * 16 + wv * 4 + jq;
                                const float4 w = *(const float4*)&lds[OWS + row * 36 + g4 * 4];
                                acc[jq*3+g] = fmaf(x3, w.w, fmaf(x2, w.z,
                                               fmaf(x1, w.y, fmaf(x0, w.x, acc[jq*3+g]))));
                            }
                        }
                    }
                    __syncthreads();
                }
            }
            // GRU fully in registers (r,z,n co-located per thread)
            #pragma unroll
            for (int jq = 0; jq < 4; ++jq) {
                const int j = j0 + wv * 4 + jq;
                const float rr = sig_(acc[jq*3+0] + b_ih[j] + b_hh[j]);
                const float zz = sig_(acc[jq*3+1] + b_ih[1024+j] + b_hh[1024+j]);
                const float nn = tanhf(acc[jq*3+2] + b_ih[2048+j] + rr * b_hh[2048+j]);
                const float h = (1.f - zz) * nn;
                hT[(size_t)j * 512 + cb + l] = h;          // coalesced b32
                lds[OHB + (wv*4+jq)*68 + l] = h;
            }
            __syncthreads();
            {   // out_h bounce
                const int b = tid >> 2, qj = tid & 3;
                if (cb + b < bsz) {
                    float4 v = { lds[OHB + (qj*4+0)*68 + b], lds[OHB + (qj*4+1)*68 + b],
                                 lds[OHB + (qj*4+2)*68 + b], lds[OHB + (qj*4+3)*68 + b] };
                    *(float4*)&out_h[(size_t)(ofs + cb + b) * 1024 + j0 + qj*4] = v;
                }
            }
            __syncthreads();
        }
        cl_sync(cnt, go, nblk, t * 3 + 1, tid);

        // ========= phase B: ha = tanh(h@Wa^T + ba) ; 64 units x 32 n =========
        for (int s = r; s < 64; s += nblk) {
            const int n0 = s * 32;
            const float* __restrict__ Wa = (n0 < 1024) ? W1a : W2a;
            const float* __restrict__ ba = (n0 < 1024) ? b1a : b2a;
            const int nr0 = n0 & 1023;
            float acc[8];
            #pragma unroll
            for (int i = 0; i < 8; ++i) acc[i] = 0.f;

            const int xk = tid >> 3, xb = (tid & 7) * 8;
            const int wrow = tid >> 3, wk4 = (tid & 7) * 4;
            float4 px0, px1, pw;
            {
                const float* xp = &hT[(size_t)xk * 512 + cb + xb];
                px0 = *(const float4*)xp; px1 = *(const float4*)(xp + 4);
                pw = *(const float4*)&Wa[(size_t)(nr0 + wrow) * 1024 + wk4];
            }
            for (int kc = 0; kc < 32; ++kc) {
                *(float4*)&lds[xk * 68 + xb]     = px0;
                *(float4*)&lds[xk * 68 + xb + 4] = px1;
                *(float4*)&lds[OWS + wrow * 36 + wk4] = pw;
                __syncthreads();
                if (kc < 31) {
                    const int kb = (kc + 1) * 32;
                    const float* xp = &hT[(size_t)(kb + xk) * 512 + cb + xb];
                    px0 = *(const float4*)xp; px1 = *(const float4*)(xp + 4);
                    pw = *(const float4*)&Wa[(size_t)(nr0 + wrow) * 1024 + kb + wk4];
                }
                #pragma unroll
                for (int g4 = 0; g4 < 8; ++g4) {
                    const float x0 = lds[(g4*4+0)*68 + l];
                    const float x1 = lds[(g4*4+1)*68 + l];
                    const float x2 = lds[(g4*4+2)*68 + l];
                    const float x3 = lds[(g4*4+3)*68 + l];
                    #pragma unroll
                    for (int q = 0; q < 8; ++q) {
                        const float4 w = *(const float4*)&lds[OWS + (wv*8+q) * 36 + g4 * 4];
                        acc[q] = fmaf(x3, w.w, fmaf(x2, w.z,
                                  fmaf(x1, w.y, fmaf(x0, w.x, acc[q]))));
                    }
                }
                __syncthreads();
            }
            #pragma unroll
            for (int q = 0; q < 8; ++q)
                haT[(size_t)(n0 + wv*8 + q) * 512 + cb + l] =
                    tanhf(acc[q] + ba[nr0 + wv*8 + q]);    // coalesced b32, no LDS
        }
        cl_sync(cnt, go, nblk, t * 3 + 2, tid);

        // ========= phase C: p = ha@Wb^T + bb ; 32 units x 8 cols (both fams) =========
        for (int s = r; s < 32; s += nblk) {
            const int c0 = s * 8;
            const int fam = wv >> 1, cg = wv & 1;
            float acc[4] = {0.f, 0.f, 0.f, 0.f};

            const int slot0 = tid, slot1 = tid + 256;
            const int fs0 = slot0 >> 8, kk0 = (slot0 >> 3) & 31, b80 = (slot0 & 7) * 8;
            const int fs1 = slot1 >> 8, kk1 = (slot1 >> 3) & 31, b81 = (slot1 & 7) * 8;
            const int fw = tid >> 6, cw = (tid >> 3) & 7, wk4 = (tid & 7) * 4;
            const float* __restrict__ Wbw = fw ? W2b : W1b;
            float4 px00, px01, px10, px11, pw;
            {
                const float* p0 = &haT[((size_t)fs0*1024 + kk0) * 512 + cb + b80];
                const float* p1 = &haT[((size_t)fs1*1024 + kk1) * 512 + cb + b81];
                px00 = *(const float4*)p0; px01 = *(const float4*)(p0 + 4);
                px10 = *(const float4*)p1; px11 = *(const float4*)(p1 + 4);
                if (tid < 128) pw = *(const float4*)&Wbw[(size_t)(c0 + cw) * 1024 + wk4];
            }
            for (int kc = 0; kc < 32; ++kc) {
                *(float4*)&lds[fs0*2176 + kk0*68 + b80]     = px00;
                *(float4*)&lds[fs0*2176 + kk0*68 + b80 + 4] = px01;
                *(float4*)&lds[fs1*2176 + kk1*68 + b81]     = px10;
                *(float4*)&lds[fs1*2176 + kk1*68 + b81 + 4] = px11;
                if (tid < 128) *(float4*)&lds[OWS + (fw*8+cw) * 36 + wk4] = pw;
                __syncthreads();
                if (kc < 31) {
                    const int kb = (kc + 1) * 32;
                    const float* p0 = &haT[((size_t)fs0*1024 + kb + kk0) * 512 + cb + b80];
                    const float* p1 = &haT[((size_t)fs1*1024 + kb + kk1) * 512 + cb + b81];
                    px00 = *(const float4*)p0; px01 = *(const float4*)(p0 + 4);
                    px10 = *(const float4*)p1; px11 = *(const float4*)(p1 + 4);
                    if (tid < 128) pw = *(const float4*)&Wbw[(size_t)(c0 + cw) * 1024 + kb + wk4];
                }
                #pragma unroll
                for (int g4 = 0; g4 < 8; ++g4) {
                    const float x0 = lds[fam*2176 + (g4*4+0)*68 + l];
                    const float x1 = lds[fam*2176 + (g4*4+1)*68 + l];
                    const float x2 = lds[fam*2176 + (g4*4+2)*68 + l];
                    const float x3 = lds[fam*2176 + (g4*4+3)*68 + l];
                    #pragma unroll
                    for (int q = 0; q < 4; ++q) {
                        const float4 w = *(const float4*)&lds[OWS + (fam*8 + cg*4 + q) * 36 + g4 * 4];
                        acc[q] = fmaf(x3, w.w, fmaf(x2, w.z,
                                  fmaf(x1, w.y, fmaf(x0, w.x, acc[q]))));
                    }
                }
                __syncthreads();
            }
            // exchange p across fams; bias in-register
            #pragma unroll
            for (int q = 0; q < 4; ++q) {
                const int cc = cg*4 + q;
                const float bias = fam ? b2b[c0 + cc] : b1b[c0 + cc];
                lds[OHB + (fam*8 + cc)*68 + l] = acc[q] + bias;
            }
            __syncthreads();
            if (fam == 0) {
                float p1v[4], p2v[4];
                #pragma unroll
                for (int q = 0; q < 4; ++q) {
                    p1v[q] = lds[OHB + (cg*4+q)*68 + l];
                    p2v[q] = lds[OHB + (8 + cg*4+q)*68 + l];
                }
                const float4 e = *(const float4*)&eps[(size_t)t*131072 + (size_t)(cb+l)*256 + c0 + cg*4];
                const float ev[4] = {e.x, e.y, e.z, e.w};
                #pragma unroll
                for (int q = 0; q < 4; ++q)
                    xT[(size_t)(c0 + cg*4 + q) * 512 + cb + l] =
                        fmaf(expf(0.5f * p2v[q]), ev[q], p1v[q]);
                if (cb + l < bsz) {
                    float4 v = { p1v[0], p1v[1], p1v[2], p1v[3] };
                    *(float4*)&out_p1[(size_t)(ofs + cb + l) * 256 + c0 + cg*4] = v;
                }
            } else {
                if (cb + l < bsz) {
                    float4 v = { lds[OHB + (8+cg*4+0)*68 + l], lds[OHB + (8+cg*4+1)*68 + l],
                                 lds[OHB + (8+cg*4+2)*68 + l], lds[OHB + (8+cg*4+3)*68 + l] };
                    *(float4*)&out_p2[(size_t)(ofs + cb + l) * 256 + c0 + cg*4] = v;
                }
            }
            __syncthreads();
        }
        cl_sync(cnt, go, nblk, t * 3 + 3, tid);
    }
}

extern "C" void kernel_launch(void* const* d_in, const int* in_sizes, int n_in,
                              void* d_out, int out_size, void* d_ws, size_t ws_size,
                              hipStream_t stream)
{
    (void)in_sizes; (void)n_in; (void)ws_size;
    const int*   lengths = (const int*)  d_in[1];
    const float* eps     = (const float*)d_in[2];
    const float* W_ih    = (const float*)d_in[5];
    const float* b_ih    = (const float*)d_in[6];
    const float* b_hh    = (const float*)d_in[8];
    const float* W1a     = (const float*)d_in[9];
    const float* b1a     = (const float*)d_in[10];
    const float* W1b     = (const float*)d_in[11];
    const float* b1b     = (const float*)d_in[12];
    const float* W2a     = (const float*)d_in[13];
    const float* b2a     = (const float*)d_in[14];
    const float* W2b     = (const float*)d_in[15];
    const float* b2b     = (const float*)d_in[16];

    float* out = (float*)d_out;
    const size_t N = (size_t)out_size / 1536;
    float* out_p1 = out;
    float* out_p2 = out + N * 256;
    float* out_h  = out + N * 512;

    int*   bar = (int*)d_ws;                      // 4 KB barrier region
    float* xT  = (float*)((char*)d_ws + 4096);    // [256][512]
    float* hT  = xT + 131072;                     // [1024][512]
    float* haT = hT + 524288;                     // [2048][512]  (~6.8 MB total)

    hipMemsetAsync(d_ws, 0, 4096, stream);

    int dev = 0;
    (void)hipGetDevice(&dev);
    int ncu = 0;
    if (hipDeviceGetAttribute(&ncu, hipDeviceAttributeMultiprocessorCount, dev) != hipSuccess || ncu <= 0)
        ncu = 256;
    int maxB = 0;
    if (hipOccupancyMaxActiveBlocksPerMultiprocessor(&maxB, (const void*)kfused, 256, 0) != hipSuccess || maxB <= 0)
        maxB = 1;
    long cap = (long)maxB * (long)ncu;
    int grd = (cap < 512) ? (int)(cap & ~7L) : 512;
    if (grd < 8) grd = 8;

    for (;;) {
        int nblk = grd >> 3;
        void* args[] = {
            (void*)&lengths, (void*)&eps, (void*)&W_ih, (void*)&b_ih, (void*)&b_hh,
            (void*)&W1a, (void*)&b1a, (void*)&W1b, (void*)&b1b,
            (void*)&W2a, (void*)&b2a, (void*)&W2b, (void*)&b2b,
            (void*)&out_p1, (void*)&out_p2, (void*)&out_h,
            (void*)&bar, (void*)&xT, (void*)&hT, (void*)&haT, (void*)&nblk
        };
        hipError_t err = hipLaunchCooperativeKernel((void*)kfused, dim3(grd), dim3(256), args, 0, stream);
        if (err == hipSuccess || grd <= 8) break;
        grd = (grd >> 1) & ~7;
        if (grd < 8) grd = 8;
    }
}

// Round 14
// 39980.096 us; speedup vs baseline: 1.5351x; 1.5351x over previous
//
#include <hip/hip_runtime.h>
#include <math.h>

#define TMAX 200
#define CB   64

__device__ __forceinline__ float sig_(float x){ return 1.0f/(1.0f+expf(-x)); }

// Light cluster barrier: one atomicAdd + go flag, single poller per block.
__device__ __forceinline__ void cl_sync(int* cnt, int* go, int nblk, int ep, int tid)
{
    __syncthreads();
    if (tid == 0) {
        __threadfence();
        int old = __hip_atomic_fetch_add(cnt, 1, __ATOMIC_ACQ_REL, __HIP_MEMORY_SCOPE_AGENT);
        if (old == nblk - 1) {
            __hip_atomic_store(cnt, 0, __ATOMIC_RELAXED, __HIP_MEMORY_SCOPE_AGENT);
            __hip_atomic_store(go, ep, __ATOMIC_RELEASE, __HIP_MEMORY_SCOPE_AGENT);
        } else {
            while (__hip_atomic_load(go, __ATOMIC_ACQUIRE, __HIP_MEMORY_SCOPE_AGENT) < ep)
                __builtin_amdgcn_s_sleep(16);
        }
        __threadfence();
    }
    __syncthreads();
}

// LDS float offsets: XS[2] @0/2432 ([32][76]); WS[2] @4864/8064 ([32][100] A, [32][68] B, [32][12] C)
// A aux: gi [96][68] @0 ; h bounce [32][68] @6528
// C aux: red [64][68] @0 ; e_lds [64][12] @4864 ; pbounce [64][20] @5700
#define LDSF 11264

__global__ __launch_bounds__(256, 2)
void kfused(const int* __restrict__ lengths,
            const float* __restrict__ eps,
            const float* __restrict__ W_ih, const float* __restrict__ b_ih,
            const float* __restrict__ b_hh,
            const float* __restrict__ W1a, const float* __restrict__ b1a,
            const float* __restrict__ W1b, const float* __restrict__ b1b,
            const float* __restrict__ W2a, const float* __restrict__ b2a,
            const float* __restrict__ W2b, const float* __restrict__ b2b,
            float* __restrict__ out_p1, float* __restrict__ out_p2, float* __restrict__ out_h,
            int* __restrict__ bar, float* __restrict__ xT, float* __restrict__ hT,
            float* __restrict__ haT, int nblk)
{
    __shared__ float lds[LDSF];
    __shared__ int sbs[TMAX], soff[TMAX];

    const int tid = threadIdx.x;
    const int bid = blockIdx.x;
    // XCD-locality mapping (the one change vs R10): cluster blocks are CONSECUTIVE
    // bids -> spread across XCDs (XCD = bid%8); same-rank blocks of all clusters
    // (same weight slice) share an XCD -> per-XCD weights 13.3/8 MB = L2-resident.
    const int cl  = bid / nblk;          // cluster (8 x 64 batches)
    const int r   = bid % nblk;          // rank within cluster = weight slice
    const int cb  = cl * CB;

    int* cnt = &bar[cl * 64];
    int* go  = &bar[cl * 64 + 16];

    if (tid < TMAX) {
        int c = 0;
        for (int b = 0; b < 512; ++b) c += (lengths[b] > tid) ? 1 : 0;
        sbs[tid] = c;
    }
    __syncthreads();
    if (tid == 0) { int a = 0; for (int i = 0; i < TMAX; ++i) { soff[i] = a; a += sbs[i]; } }
    __syncthreads();

    for (int t = 0; t < TMAX; ++t) {
        const int bsz = sbs[t], ofs = soff[t];

        // ================= phase A: gi = x @ W_ih^T -> GRU -> h =================
        for (int s = r; s < 32; s += nblk) {
            const int j0 = s * 32;
            const int tx = tid & 15, ty = tid >> 4;
            float acc[4][6];
            #pragma unroll
            for (int i = 0; i < 4; ++i)
                #pragma unroll
                for (int q = 0; q < 6; ++q) acc[i][q] = 0.f;

            if (t > 0) {
                const int sk = tid >> 3, sb = (tid & 7) * 8;
                const int wj = tid >> 3, wk = (tid & 7) * 4;
                float4 px0, px1, pw0, pw1, pw2;
                px0 = *(const float4*)&xT[(size_t)sk * 512 + cb + sb];
                px1 = *(const float4*)&xT[(size_t)sk * 512 + cb + sb + 4];
                pw0 = *(const float4*)&W_ih[(size_t)(j0 + wj) * 256 + wk];
                pw1 = *(const float4*)&W_ih[(size_t)(1024 + j0 + wj) * 256 + wk];
                pw2 = *(const float4*)&W_ih[(size_t)(2048 + j0 + wj) * 256 + wk];
                {
                    float* xs = lds; float* ws = lds + 4864;
                    *(float4*)&xs[sk * 76 + sb] = px0;
                    *(float4*)&xs[sk * 76 + sb + 4] = px1;
                    const float* a0 = &pw0.x; const float* a1 = &pw1.x; const float* a2 = &pw2.x;
                    #pragma unroll
                    for (int m = 0; m < 4; ++m) {
                        ws[(wk+m)*100 + wj]      = a0[m];
                        ws[(wk+m)*100 + 32 + wj] = a1[m];
                        ws[(wk+m)*100 + 64 + wj] = a2[m];
                    }
                }
                for (int kc = 0; kc < 8; ++kc) {
                    __syncthreads();
                    const int cur = kc & 1;
                    if (kc < 7) {
                        const int kb = (kc + 1) * 32;
                        px0 = *(const float4*)&xT[(size_t)(kb + sk) * 512 + cb + sb];
                        px1 = *(const float4*)&xT[(size_t)(kb + sk) * 512 + cb + sb + 4];
                        pw0 = *(const float4*)&W_ih[(size_t)(j0 + wj) * 256 + kb + wk];
                        pw1 = *(const float4*)&W_ih[(size_t)(1024 + j0 + wj) * 256 + kb + wk];
                        pw2 = *(const float4*)&W_ih[(size_t)(2048 + j0 + wj) * 256 + kb + wk];
                    }
                    const float* xs = lds + cur * 2432;
                    const float* ws = lds + 4864 + cur * 3200;
                    #pragma unroll 4
                    for (int kk = 0; kk < 32; ++kk) {
                        const float4 a4 = *(const float4*)&xs[kk * 76 + ty * 4];
                        float w[6];
                        #pragma unroll
                        for (int q = 0; q < 6; ++q) w[q] = ws[kk * 100 + tx * 6 + q];
                        const float av[4] = {a4.x, a4.y, a4.z, a4.w};
                        #pragma unroll
                        for (int i = 0; i < 4; ++i)
                            #pragma unroll
                            for (int q = 0; q < 6; ++q)
                                acc[i][q] = fmaf(av[i], w[q], acc[i][q]);
                    }
                    if (kc < 7) {
                        float* xs2 = lds + (cur ^ 1) * 2432;
                        float* ws2 = lds + 4864 + (cur ^ 1) * 3200;
                        *(float4*)&xs2[sk * 76 + sb] = px0;
                        *(float4*)&xs2[sk * 76 + sb + 4] = px1;
                        const float* a0 = &pw0.x; const float* a1 = &pw1.x; const float* a2 = &pw2.x;
                        #pragma unroll
                        for (int m = 0; m < 4; ++m) {
                            ws2[(wk+m)*100 + wj]      = a0[m];
                            ws2[(wk+m)*100 + 32 + wj] = a1[m];
                            ws2[(wk+m)*100 + 64 + wj] = a2[m];
                        }
                    }
                }
            }
            __syncthreads();
            // gi -> lds[96][68]
            #pragma unroll
            for (int q = 0; q < 6; ++q) {
                const int n = tx * 6 + q;
                #pragma unroll
                for (int i = 0; i < 4; ++i) lds[n * 68 + ty * 4 + i] = acc[i][q];
            }
            __syncthreads();
            // GRU + hT write + h bounce
            {
                const int jr = tid & 31, bq = (tid >> 5) * 8;
                const int j = j0 + jr;
                const float brr = b_ih[j] + b_hh[j];
                const float bzz = b_ih[1024 + j] + b_hh[1024 + j];
                const float bnn = b_ih[2048 + j];
                const float gnn = b_hh[2048 + j];
                float hv[8];
                #pragma unroll
                for (int i = 0; i < 8; ++i) {
                    const int b = bq + i;
                    const float rr = sig_(lds[jr * 68 + b] + brr);
                    const float zz = sig_(lds[(32 + jr) * 68 + b] + bzz);
                    const float nn = tanhf(lds[(64 + jr) * 68 + b] + bnn + rr * gnn);
                    hv[i] = (1.f - zz) * nn;
                    hT[(size_t)j * 512 + cb + b] = hv[i];
                }
                #pragma unroll
                for (int i = 0; i < 8; ++i) lds[6528 + jr * 68 + bq + i] = hv[i];
            }
            __syncthreads();
            {
                const int b = tid >> 2, q = tid & 3;
                if (cb + b < bsz) {
                    float4 v0, v1;
                    v0.x = lds[6528 + (q*8+0)*68 + b]; v0.y = lds[6528 + (q*8+1)*68 + b];
                    v0.z = lds[6528 + (q*8+2)*68 + b]; v0.w = lds[6528 + (q*8+3)*68 + b];
                    v1.x = lds[6528 + (q*8+4)*68 + b]; v1.y = lds[6528 + (q*8+5)*68 + b];
                    v1.z = lds[6528 + (q*8+6)*68 + b]; v1.w = lds[6528 + (q*8+7)*68 + b];
                    *(float4*)&out_h[(size_t)(ofs + cb + b) * 1024 + j0 + q * 8] = v0;
                    *(float4*)&out_h[(size_t)(ofs + cb + b) * 1024 + j0 + q * 8 + 4] = v1;
                }
            }
            __syncthreads();
        }
        cl_sync(cnt, go, nblk, t * 3 + 1, tid);

        // ================= phase B: ha = tanh(h @ Wa^T + ba) =================
        for (int s = r; s < 32; s += nblk) {
            const int n0 = s * 64;
            const float* __restrict__ Wa = (n0 < 1024) ? W1a : W2a;
            const float* __restrict__ ba = (n0 < 1024) ? b1a : b2a;
            const int nr0 = n0 & 1023;
            const int tx = tid & 15, ty = tid >> 4;
            const int sk = tid >> 3, sb = (tid & 7) * 8;
            const int wn = tid >> 2, wk0 = (tid & 3) * 8;
            float acc[4][4];
            #pragma unroll
            for (int i = 0; i < 4; ++i)
                #pragma unroll
                for (int j = 0; j < 4; ++j) acc[i][j] = 0.f;

            float4 px0, px1, pw0, pw1;
            px0 = *(const float4*)&hT[(size_t)sk * 512 + cb + sb];
            px1 = *(const float4*)&hT[(size_t)sk * 512 + cb + sb + 4];
            pw0 = *(const float4*)&Wa[(size_t)(nr0 + wn) * 1024 + wk0];
            pw1 = *(const float4*)&Wa[(size_t)(nr0 + wn) * 1024 + wk0 + 4];
            {
                float* xs = lds; float* ws = lds + 4864;
                *(float4*)&xs[sk * 76 + sb] = px0;
                *(float4*)&xs[sk * 76 + sb + 4] = px1;
                const float* a0 = &pw0.x; const float* a1 = &pw1.x;
                #pragma unroll
                for (int m = 0; m < 4; ++m) {
                    ws[(wk0+m)*68 + wn]   = a0[m];
                    ws[(wk0+4+m)*68 + wn] = a1[m];
                }
            }
            for (int kc = 0; kc < 32; ++kc) {
                __syncthreads();
                const int cur = kc & 1;
                if (kc < 31) {
                    const int kb = (kc + 1) * 32;
                    px0 = *(const float4*)&hT[(size_t)(kb + sk) * 512 + cb + sb];
                    px1 = *(const float4*)&hT[(size_t)(kb + sk) * 512 + cb + sb + 4];
                    pw0 = *(const float4*)&Wa[(size_t)(nr0 + wn) * 1024 + kb + wk0];
                    pw1 = *(const float4*)&Wa[(size_t)(nr0 + wn) * 1024 + kb + wk0 + 4];
                }
                const float* xs = lds + cur * 2432;
                const float* ws = lds + 4864 + cur * 3200;
                #pragma unroll 4
                for (int kk = 0; kk < 32; ++kk) {
                    const float4 a4 = *(const float4*)&xs[kk * 76 + ty * 4];
                    const float4 w4 = *(const float4*)&ws[kk * 68 + tx * 4];
                    const float av[4] = {a4.x, a4.y, a4.z, a4.w};
                    const float wv[4] = {w4.x, w4.y, w4.z, w4.w};
                    #pragma unroll
                    for (int i = 0; i < 4; ++i)
                        #pragma unroll
                        for (int j = 0; j < 4; ++j)
                            acc[i][j] = fmaf(av[i], wv[j], acc[i][j]);
                }
                if (kc < 31) {
                    float* xs2 = lds + (cur ^ 1) * 2432;
                    float* ws2 = lds + 4864 + (cur ^ 1) * 3200;
                    *(float4*)&xs2[sk * 76 + sb] = px0;
                    *(float4*)&xs2[sk * 76 + sb + 4] = px1;
                    const float* a0 = &pw0.x; const float* a1 = &pw1.x;
                    #pragma unroll
                    for (int m = 0; m < 4; ++m) {
                        ws2[(wk0+m)*68 + wn]   = a0[m];
                        ws2[(wk0+4+m)*68 + wn] = a1[m];
                    }
                }
            }
            #pragma unroll
            for (int j = 0; j < 4; ++j) {
                const float bias = ba[nr0 + tx * 4 + j];
                float4 hv;
                hv.x = tanhf(acc[0][j] + bias);
                hv.y = tanhf(acc[1][j] + bias);
                hv.z = tanhf(acc[2][j] + bias);
                hv.w = tanhf(acc[3][j] + bias);
                *(float4*)&haT[(size_t)(n0 + tx * 4 + j) * 512 + cb + ty * 4] = hv;
            }
            __syncthreads();
        }
        cl_sync(cnt, go, nblk, t * 3 + 2, tid);

        // ===== phase C: p = ha @ Wb^T + bb (8 cols, both fams); scatter; x-fuse =====
        for (int s = r; s < 32; s += nblk) {
            const int c0 = s * 8;
            const int g = tid >> 6, b = tid & 63;
            const int sk = tid >> 3, sb = (tid & 7) * 8;
            float accf[2][8];
            #pragma unroll
            for (int f = 0; f < 2; ++f)
                #pragma unroll
                for (int c = 0; c < 8; ++c) accf[f][c] = 0.f;

            #pragma unroll 1
            for (int f = 0; f < 2; ++f) {
                const float* __restrict__ Wb = f ? W2b : W1b;
                const float* __restrict__ hap = haT + (size_t)f * 1024 * 512;
                float4 px0, px1, pwv;
                px0 = *(const float4*)&hap[(size_t)sk * 512 + cb + sb];
                px1 = *(const float4*)&hap[(size_t)sk * 512 + cb + sb + 4];
                const int cw = (tid & 63) >> 3, ck = (tid & 7) * 4;
                if (tid < 64) pwv = *(const float4*)&Wb[(size_t)(c0 + cw) * 1024 + ck];
                {
                    float* xs = lds; float* ws = lds + 4864;
                    *(float4*)&xs[sk * 76 + sb] = px0;
                    *(float4*)&xs[sk * 76 + sb + 4] = px1;
                    if (tid < 64) {
                        const float* a0 = &pwv.x;
                        #pragma unroll
                        for (int m = 0; m < 4; ++m) ws[(ck+m)*12 + cw] = a0[m];
                    }
                }
                for (int kc = 0; kc < 32; ++kc) {
                    __syncthreads();
                    const int cur = kc & 1;
                    if (kc < 31) {
                        const int kb = (kc + 1) * 32;
                        px0 = *(const float4*)&hap[(size_t)(kb + sk) * 512 + cb + sb];
                        px1 = *(const float4*)&hap[(size_t)(kb + sk) * 512 + cb + sb + 4];
                        if (tid < 64) pwv = *(const float4*)&Wb[(size_t)(c0 + cw) * 1024 + kb + ck];
                    }
                    const float* xs = lds + cur * 2432;
                    const float* ws = lds + 4864 + cur * 3200;
                    #pragma unroll
                    for (int k8 = 0; k8 < 8; ++k8) {
                        const int kk = g * 8 + k8;
                        const float a = xs[kk * 76 + b];
                        const float4 wlo = *(const float4*)&ws[kk * 12];
                        const float4 whi = *(const float4*)&ws[kk * 12 + 4];
                        accf[f][0] = fmaf(a, wlo.x, accf[f][0]);
                        accf[f][1] = fmaf(a, wlo.y, accf[f][1]);
                        accf[f][2] = fmaf(a, wlo.z, accf[f][2]);
                        accf[f][3] = fmaf(a, wlo.w, accf[f][3]);
                        accf[f][4] = fmaf(a, whi.x, accf[f][4]);
                        accf[f][5] = fmaf(a, whi.y, accf[f][5]);
                        accf[f][6] = fmaf(a, whi.z, accf[f][6]);
                        accf[f][7] = fmaf(a, whi.w, accf[f][7]);
                    }
                    if (kc < 31) {
                        float* xs2 = lds + (cur ^ 1) * 2432;
                        float* ws2 = lds + 4864 + (cur ^ 1) * 3200;
                        *(float4*)&xs2[sk * 76 + sb] = px0;
                        *(float4*)&xs2[sk * 76 + sb + 4] = px1;
                        if (tid < 64) {
                            const float* a0 = &pwv.x;
                            #pragma unroll
                            for (int m = 0; m < 4; ++m) ws2[(ck+m)*12 + cw] = a0[m];
                        }
                    }
                }
            }
            __syncthreads();
            // red[(f*4+g)*8+c][68] + e_lds
            #pragma unroll
            for (int c = 0; c < 8; ++c) {
                lds[((0 * 4 + g) * 8 + c) * 68 + b] = accf[0][c];
                lds[((1 * 4 + g) * 8 + c) * 68 + b] = accf[1][c];
            }
            {
                const int b2 = tid >> 2, q = tid & 3;
                const float2 e = *(const float2*)&eps[(size_t)t * 131072 + (size_t)(cb + b2) * 256 + c0 + q * 2];
                lds[4864 + b2 * 12 + q * 2]     = e.x;
                lds[4864 + b2 * 12 + q * 2 + 1] = e.y;
            }
            __syncthreads();
            {
                const int cp = tid >> 6;
                #pragma unroll
                for (int e = 0; e < 2; ++e) {
                    const int cc = cp * 2 + e;
                    float p1 = b1b[c0 + cc], p2 = b2b[c0 + cc];
                    #pragma unroll
                    for (int gg = 0; gg < 4; ++gg) {
                        p1 += lds[((0 * 4 + gg) * 8 + cc) * 68 + b];
                        p2 += lds[((1 * 4 + gg) * 8 + cc) * 68 + b];
                    }
                    const float x = fmaf(expf(0.5f * p2), lds[4864 + b * 12 + cc], p1);
                    xT[(size_t)(c0 + cc) * 512 + cb + b] = x;
                    lds[5700 + b * 20 + cc]     = p1;
                    lds[5700 + b * 20 + 8 + cc] = p2;
                }
            }
            __syncthreads();
            {
                const int bb2 = tid >> 2, q = tid & 3;
                if (cb + bb2 < bsz) {
                    if (q < 2) {
                        *(float4*)&out_p1[(size_t)(ofs + cb + bb2) * 256 + c0 + q * 4] =
                            *(const float4*)&lds[5700 + bb2 * 20 + q * 4];
                    } else {
                        *(float4*)&out_p2[(size_t)(ofs + cb + bb2) * 256 + c0 + (q - 2) * 4] =
                            *(const float4*)&lds[5700 + bb2 * 20 + 8 + (q - 2) * 4];
                    }
                }
            }
            __syncthreads();
        }
        cl_sync(cnt, go, nblk, t * 3 + 3, tid);
    }
}

extern "C" void kernel_launch(void* const* d_in, const int* in_sizes, int n_in,
                              void* d_out, int out_size, void* d_ws, size_t ws_size,
                              hipStream_t stream)
{
    (void)in_sizes; (void)n_in; (void)ws_size;
    const int*   lengths = (const int*)  d_in[1];
    const float* eps     = (const float*)d_in[2];
    const float* W_ih    = (const float*)d_in[5];
    const float* b_ih    = (const float*)d_in[6];
    const float* b_hh    = (const float*)d_in[8];
    const float* W1a     = (const float*)d_in[9];
    const float* b1a     = (const float*)d_in[10];
    const float* W1b     = (const float*)d_in[11];
    const float* b1b     = (const float*)d_in[12];
    const float* W2a     = (const float*)d_in[13];
    const float* b2a     = (const float*)d_in[14];
    const float* W2b     = (const float*)d_in[15];
    const float* b2b     = (const float*)d_in[16];

    float* out = (float*)d_out;
    const size_t N = (size_t)out_size / 1536;
    float* out_p1 = out;
    float* out_p2 = out + N * 256;
    float* out_h  = out + N * 512;

    int*   bar = (int*)d_ws;                      // 4 KB barrier region
    float* xT  = (float*)((char*)d_ws + 4096);    // [256][512]
    float* hT  = xT + 131072;                     // [1024][512]
    float* haT = hT + 524288;                     // [2048][512]  (~6.8 MB total)

    hipMemsetAsync(d_ws, 0, 4096, stream);

    int dev = 0;
    (void)hipGetDevice(&dev);
    int ncu = 0;
    if (hipDeviceGetAttribute(&ncu, hipDeviceAttributeMultiprocessorCount, dev) != hipSuccess || ncu <= 0)
        ncu = 256;
    int maxB = 0;
    if (hipOccupancyMaxActiveBlocksPerMultiprocessor(&maxB, (const void*)kfused, 256, 0) != hipSuccess || maxB <= 0)
        maxB = 1;
    long cap = (long)maxB * (long)ncu;
    int grd = (cap < 256) ? (int)(cap & ~7L) : 256;
    if (grd < 8) grd = 8;

    for (;;) {
        int nblk = grd >> 3;
        void* args[] = {
            (void*)&lengths, (void*)&eps, (void*)&W_ih, (void*)&b_ih, (void*)&b_hh,
            (void*)&W1a, (void*)&b1a, (void*)&W1b, (void*)&b1b,
            (void*)&W2a, (void*)&b2a, (void*)&W2b, (void*)&b2b,
            (void*)&out_p1, (void*)&out_p2, (void*)&out_h,
            (void*)&bar, (void*)&xT, (void*)&hT, (void*)&haT, (void*)&nblk
        };
        hipError_t err = hipLaunchCooperativeKernel((void*)kfused, dim3(grd), dim3(256), args, 0, stream);
        if (err == hipSuccess || grd <= 8) break;
        grd = (grd >> 1) & ~7;
        if (grd < 8) grd = 8;
    }
}